// Round 6
// baseline (1104.102 us; speedup 1.0000x reference)
//
#include <hip/hip_runtime.h>
#include <hip/hip_bf16.h>
#include <math.h>

#define BB 16
#define TT 512
#define VV 2048
#define DD 512
#define HDD 64
#define LL 6
#define FF 2048
#define BT 8192   // B*T

typedef __hip_bfloat16 bf16;
typedef __attribute__((ext_vector_type(8))) short bf8s;   // 8 bf16 (4 VGPRs)
typedef __attribute__((ext_vector_type(4))) float f4;     // C/D frag

__device__ __forceinline__ float cvt(float x){ return x; }
__device__ __forceinline__ float cvt(bf16 x){ return __bfloat162float(x); }

// ---------------- dtype flag: g1 all-ones. f32 1.0f -> u16 {0,0x3F80}; bf16 1.0 -> 0x3F80 ----------------
__global__ void k_flag(const void* g1, int* flagp){
  if(threadIdx.x==0 && blockIdx.x==0){
    const unsigned short* u = (const unsigned short*)g1;
    *flagp = (u[0] == 0) ? 1 : 0;   // 1 = inputs f32, 0 = bf16
  }
}

// ---------------- convert flag-typed input to bf16 copy ----------------
__global__ __launch_bounds__(256) void k_cvt(const void* __restrict__ src,
                                             bf16* __restrict__ dst, int n,
                                             const int* __restrict__ flagp){
  int i = blockIdx.x*256 + threadIdx.x;
  if(i >= n) return;
  if(*flagp) dst[i] = (bf16)(((const float*)src)[i]);
  else       dst[i] = ((const bf16*)src)[i];
}

// ---------------- pack QKV biases: [L][64]x3 -> [L][3][64] bf16 ----------------
__global__ void k_packb(const void* bq, const void* bk, const void* bv,
                        bf16* dst, const int* flagp){
  int i = blockIdx.x*256 + threadIdx.x;
  if(i >= LL*192) return;
  int l = i/192, r = i%192, j = r>>6, hh = r&63;
  const void* s = (j==0)?bq:((j==1)?bk:bv);
  float v = (*flagp) ? ((const float*)s)[l*64+hh] : cvt(((const bf16*)s)[l*64+hh]);
  dst[i] = (bf16)v;
}

// ---------------- tiled transpose: src [z][R][C] -> dst [z][C][R(ldD)] bf16 ----------------
__global__ __launch_bounds__(256) void k_tr(const void* __restrict__ src, bf16* __restrict__ dst,
                                            int R, int C, long long sS, long long sD, int ldD,
                                            const int* __restrict__ flagp){
  __shared__ bf16 t[32][33];
  int z = blockIdx.z;
  int c0 = blockIdx.x*32, r0 = blockIdx.y*32;
  int tx = threadIdx.x & 31, ty = threadIdx.x >> 5;   // 32 x 8
  bool isf = flagp && (*flagp);
  const float* sf = (const float*)src;
  const bf16*  sb = (const bf16*)src;
  for(int i=ty; i<32; i+=8){
    size_t off = (size_t)z*sS + (size_t)(r0+i)*C + (c0+tx);
    float v = isf ? sf[off] : cvt(sb[off]);
    t[i][tx] = (bf16)v;
  }
  __syncthreads();
  for(int i=ty; i<32; i+=8){
    dst[(size_t)z*sD + (size_t)(c0+i)*ldD + (r0+tx)] = t[tx][i];
  }
}

// ---------------- wsT_all[l][d][h] = sum_n Wo[l][n*64+h][d], all layers ----------------
__global__ __launch_bounds__(256) void k_wsumT(const void* __restrict__ Wo,
                                               bf16* __restrict__ wsT,
                                               const int* __restrict__ flagp){
  int i = blockIdx.x*256 + threadIdx.x;   // 6*64*512
  if(i >= LL*64*512) return;
  int l = i >> 15, j = i & 32767, hh = j>>9, d = j&511;
  size_t loff = (size_t)l*512*512;
  bool isf = *flagp;
  float a = 0.f;
  #pragma unroll
  for(int n=0;n<8;++n){
    size_t idx = loff + (size_t)(n*64+hh)*512 + d;
    a += isf ? ((const float*)Wo)[idx] : cvt(((const bf16*)Wo)[idx]);
  }
  wsT[(size_t)l*32768 + d*64 + hh] = (bf16)a;
}

// ---------------- fill VbT_aug cols 512..575 with rel^T (m<17) else 0 ----------------
__global__ __launch_bounds__(256) void k_relfill(const bf16* __restrict__ rel,
                                                 bf16* __restrict__ vt){
  int i = blockIdx.x*256 + threadIdx.x;   // 16*64*64
  if(i >= BB*64*64) return;
  int z = i >> 12, rest = i & 4095, hh = rest >> 6, j = rest & 63;
  vt[(size_t)z*64*576 + (size_t)hh*576 + 512 + j] = (j<17) ? rel[j*64+hh] : (bf16)0.f;
}

// ---------------- embed + positional encoding: h = 2*emb[idx] + pe ----------------
__global__ __launch_bounds__(256) void k_embed(const int* __restrict__ idx,
                                               const void* __restrict__ emb,
                                               float* __restrict__ h,
                                               const int* __restrict__ flagp){
  int r = blockIdx.x;
  int t = r & (TT-1);
  int tok = idx[r];
  bool isf = *flagp;
  for(int d = threadIdx.x; d < DD; d += 256){
    int p = d >> 1;
    float ang = (float)t * powf(10000.f, -(float)p * (1.f/128.f));
    float pe = (d & 1) ? cosf(ang) : sinf(ang);
    size_t off = (size_t)tok*DD + d;
    float ev = isf ? ((const float*)emb)[off] : cvt(((const bf16*)emb)[off]);
    h[(size_t)r*DD + d] = 2.f*ev + pe;
  }
}

// ---------------- LayerNorm (biased var): f32 in, bf16 out ----------------
__global__ __launch_bounds__(256) void k_ln(const float* __restrict__ x,
                                            const bf16* __restrict__ g,
                                            const bf16* __restrict__ b,
                                            bf16* __restrict__ y){
  int r = blockIdx.x;
  int tid = threadIdx.x;
  const float* xr = x + (size_t)r*DD;
  float v0 = xr[tid], v1 = xr[tid+256];
  float s = v0+v1, s2 = v0*v0 + v1*v1;
  for(int o=32;o;o>>=1){ s += __shfl_down(s,o); s2 += __shfl_down(s2,o); }
  __shared__ float red[8];
  int wv = tid>>6, ln = tid&63;
  if(ln==0){ red[wv]=s; red[4+wv]=s2; }
  __syncthreads();
  float a  = red[0]+red[1]+red[2]+red[3];
  float a2 = red[4]+red[5]+red[6]+red[7];
  float m  = a*(1.f/DD);
  float var = a2*(1.f/DD) - m*m;
  float inv = rsqrtf(var + 1e-5f);
  y[(size_t)r*DD+tid]     = (bf16)((v0-m)*inv*cvt(g[tid])     + cvt(b[tid]));
  y[(size_t)r*DD+tid+256] = (bf16)((v1-m)*inv*cvt(g[tid+256]) + cvt(b[tid+256]));
}

// ---------------- f32 -> bf16 ----------------
__global__ __launch_bounds__(256) void k_f2b(const float* __restrict__ x, bf16* __restrict__ o, int n){
  int i = blockIdx.x*256 + threadIdx.x;
  if(i < n) o[i] = (bf16)x[i];
}

// =====================  MFMA GEMM  =====================
// C[M,N] (=|+=) A[M,K] @ Bt[N,K]^T, bf16 inputs, f32 accum.
// 1-D grid per z-plane with bijective XCD-chunked swizzle (x fastest inside a chunk).
// CMODE: 0 = bf16 store, 1 = f32 store (+RESID reads f32), 2 = dual via flag.
template<int BM,int BN,int BK,int WM,int WN,int CMODE,bool RELU,bool RESID>
__global__ __launch_bounds__(256) void mm(const bf16* __restrict__ A,
                                          const bf16* __restrict__ Bt,
                                          void* __restrict__ Cv,
                                          const bf16* __restrict__ bias,
                                          int M, int N, int K,
                                          long long sA, long long sB, long long sC, int sBias,
                                          int gx,
                                          const int* __restrict__ flagp){
  constexpr int FM  = BM/(WM*16);
  constexpr int FN  = BN/(WN*16);
  constexpr int LDK = BK + 8;                 // +16B pad: frag reads 2-way conflict (free)
  constexpr int ACH = (BM*BK/8)/256;
  constexpr int BCH = (BN*BK/8)/256;
  __shared__ bf16 Al[BM*LDK];
  __shared__ bf16 Bl[BN*LDK];
  // XCD-chunked bijective swizzle (m204): contiguous wg range per XCD
  int nwg = gridDim.x;
  int bid = blockIdx.x;
  int q = nwg >> 3, rr = nwg & 7;
  int xcd = bid & 7, ii = bid >> 3;
  int wg = (xcd < rr ? xcd*(q+1) : rr*(q+1) + (xcd-rr)*q) + ii;
  int bx = wg % gx, by = wg / gx;
  int z = blockIdx.z;
  A  += (size_t)z*sA;
  Bt += (size_t)z*sB;
  if(bias) bias += (size_t)z*sBias;
  int tid = threadIdx.x, lane = tid&63, w = tid>>6;
  int wrow = (w/WN)*(BM/WM), wcol = (w%WN)*(BN/WN);
  int m0 = by*BM, n0 = bx*BN;
  int l15 = lane&15, l4 = lane>>4;
  int nk = K/BK;
  bf8s ra[ACH], rb[BCH];
  auto loadT = [&](int kt){
    #pragma unroll
    for(int i=0;i<ACH;++i){ int c = tid + i*256; int row=c>>3, kg=c&7;
      ra[i] = *(const bf8s*)(A + (size_t)(m0+row)*K + kt*BK + kg*8); }
    #pragma unroll
    for(int i=0;i<BCH;++i){ int c = tid + i*256; int row=c>>3, kg=c&7;
      rb[i] = *(const bf8s*)(Bt + (size_t)(n0+row)*K + kt*BK + kg*8); }
  };
  f4 acc[FM][FN] = {};
  loadT(0);
  for(int kt=0; kt<nk; ++kt){
    __syncthreads();
    #pragma unroll
    for(int i=0;i<ACH;++i){ int c = tid + i*256; int row=c>>3, kg=c&7;
      *(bf8s*)(&Al[row*LDK + kg*8]) = ra[i]; }
    #pragma unroll
    for(int i=0;i<BCH;++i){ int c = tid + i*256; int row=c>>3, kg=c&7;
      *(bf8s*)(&Bl[row*LDK + kg*8]) = rb[i]; }
    __syncthreads();
    if(kt+1 < nk) loadT(kt+1);
    #pragma unroll
    for(int g=0; g<BK/32; ++g){
      bf8s af[FM], bfr[FN];
      #pragma unroll
      for(int i=0;i<FM;++i)
        af[i] = *(const bf8s*)(&Al[(wrow + i*16 + l15)*LDK + g*32 + l4*8]);
      #pragma unroll
      for(int j=0;j<FN;++j)
        bfr[j] = *(const bf8s*)(&Bl[(wcol + j*16 + l15)*LDK + g*32 + l4*8]);
      #pragma unroll
      for(int i=0;i<FM;++i)
        #pragma unroll
        for(int j=0;j<FN;++j)
          acc[i][j] = __builtin_amdgcn_mfma_f32_16x16x32_bf16(af[i], bfr[j], acc[i][j], 0,0,0);
    }
  }
  bool f32o = (CMODE==2) ? (*flagp != 0) : (CMODE==1);
  #pragma unroll
  for(int i=0;i<FM;++i){
    #pragma unroll
    for(int j=0;j<FN;++j){
      int col = n0 + wcol + j*16 + l15;
      float bv = bias ? cvt(bias[col]) : 0.f;
      #pragma unroll
      for(int q2=0;q2<4;++q2){
        int row = m0 + wrow + i*16 + l4*4 + q2;
        size_t off = (size_t)z*sC + (size_t)row*N + col;
        float v = acc[i][j][q2] + bv;
        if(RESID) v += ((const float*)Cv)[off];
        if(RELU)  v = fmaxf(v, 0.f);
        if(CMODE==0)      ((bf16*)Cv)[off] = (bf16)v;
        else if(CMODE==1) ((float*)Cv)[off] = v;
        else { if(f32o) ((float*)Cv)[off] = v; else ((bf16*)Cv)[off] = (bf16)v; }
      }
    }
  }
}

// ---------------- softmax: bf16 scores + Qrel (merged) + causal + aug-row write ----------------
// scores bf16 [16][512][512]; att_aug bf16 [16][512][576]: cols 0..511 = p, 512..528 = bucket sums, 529..575 = 0
__global__ __launch_bounds__(256) void k_softmax(const bf16* __restrict__ scores,
                                                 const bf16* __restrict__ Q,
                                                 const bf16* __restrict__ rel,   // layer base [33][64]
                                                 bf16* __restrict__ att){
  int r = blockIdx.x;            // b*512 + t
  int t = r & 511;
  int tid = threadIdx.x;
  __shared__ float qs[64], qrs[17], red[8], am_s[17];
  if(tid >= 128 && tid < 192) qs[tid-128] = cvt(Q[(size_t)r*64 + (tid-128)]);
  if(tid >= 32 && tid < 49) am_s[tid-32] = 0.f;
  __syncthreads();
  if(tid < 17){
    float a = 0.f;
    #pragma unroll
    for(int hh=0;hh<64;++hh) a += qs[hh]*cvt(rel[tid*64+hh]);
    qrs[tid] = a;
  }
  __syncthreads();
  const bf16* srow = scores + (size_t)r*512;
  float sc[2];
  #pragma unroll
  for(int ii=0; ii<2; ++ii){
    int s = tid + ii*256;
    float v = -INFINITY;
    if(s <= t){
      int m = s - t + 16; m = m < 0 ? 0 : m;
      v = (cvt(srow[s]) + qrs[m])*0.125f;
    }
    sc[ii] = v;
  }
  int wv = tid>>6, ln = tid&63;
  float mx = fmaxf(sc[0], sc[1]);
  for(int o=32;o;o>>=1) mx = fmaxf(mx, __shfl_down(mx,o));
  if(ln==0) red[wv]=mx;
  __syncthreads();
  float M = fmaxf(fmaxf(red[0],red[1]),fmaxf(red[2],red[3]));
  float e0 = expf(sc[0]-M), e1 = expf(sc[1]-M);   // expf(-inf)=0 handles mask
  float sum = e0+e1;
  for(int o=32;o;o>>=1) sum += __shfl_down(sum,o);
  __syncthreads();
  if(ln==0) red[wv]=sum;
  __syncthreads();
  float rs = 1.f/(red[0]+red[1]+red[2]+red[3]);
  bf16* arow = att + (size_t)r*576;
  float part0 = 0.f;
  #pragma unroll
  for(int ii=0;ii<2;++ii){
    int s = tid + ii*256;
    float p = (ii==0 ? e0 : e1)*rs;
    arow[s] = (bf16)p;
    if(s <= t){
      int m = s - t + 16;
      if(m <= 0) part0 += p;      // bucket 0: all s <= t-16
      else       am_s[m] = p;     // unique s per bucket -> no race
    }
  }
  for(int o=32;o;o>>=1) part0 += __shfl_down(part0,o);
  __syncthreads();
  if(ln==0) red[wv]=part0;
  __syncthreads();
  if(tid==0) am_s[0] = red[0]+red[1]+red[2]+red[3];
  __syncthreads();
  if(tid<64) arow[512+tid] = (tid<17) ? (bf16)am_s[tid] : (bf16)0.f;
}

extern "C" void kernel_launch(void* const* d_in, const int* in_sizes, int n_in,
                              void* d_out, int out_size, void* d_ws, size_t ws_size,
                              hipStream_t stream){
  const int* idx = (const int*)d_in[0];

  char* p = (char*)d_ws;
  auto alloc = [&](size_t bytes)->char*{ char* r = p; p += (bytes + 255) & ~(size_t)255; return r; };

  int*  flag  = (int*)alloc(4);
  bf16* rel_b = (bf16*)alloc(12672*2);
  bf16* bo_b  = (bf16*)alloc(3072*2);
  bf16* g1_b  = (bf16*)alloc(3072*2);
  bf16* be1_b = (bf16*)alloc(3072*2);
  bf16* g2_b  = (bf16*)alloc(3072*2);
  bf16* be2_b = (bf16*)alloc(3072*2);
  bf16* b1_b  = (bf16*)alloc(12288*2);
  bf16* b2_b  = (bf16*)alloc(3072*2);
  bf16* bout_b= (bf16*)alloc(2048*2);
  bf16* bqkv  = (bf16*)alloc(LL*192*2);
  bf16* WqkvT = (bf16*)alloc((size_t)LL*3*64*512*2);    // [L][3][64][512]
  bf16* W1T   = (bf16*)alloc((size_t)LL*2048*512*2);    // [L][2048][512]
  bf16* W2T   = (bf16*)alloc((size_t)LL*512*2048*2);    // [L][512][2048]
  bf16* WoutT = (bf16*)alloc((size_t)2048*512*2);       // [2048][512]
  bf16* wsT_all=(bf16*)alloc((size_t)LL*512*64*2);      // [L][512][64]
  float* h    = (float*)alloc((size_t)BT*DD*4);         // 16 MB
  bf16*  y    = (bf16*) alloc((size_t)BB*512*576*2);    // 9.4 MB (y | att_aug | hb union)
  bf16*  att  = y;                                      // att_aug [16][512][576]
  bf16*  hb   = y;
  bf16*  QKV  = (bf16*) alloc((size_t)3*BT*64*2);       // Q|K|V contiguous
  bf16*  vals = (bf16*) alloc((size_t)BT*64*2);
  bf16*  VbT  = (bf16*) alloc((size_t)BB*64*576*2);     // [16][64][576] (V^T | rel^T aug)
  // d_out scratch (disjoint lifetimes): scores bf16 8.4 MB -> mid bf16 33.5 MB -> final output
  bf16* scores = (bf16*)d_out;
  bf16* mid    = (bf16*)d_out;
  bf16* Qb = QKV, *Kb = QKV + (size_t)BT*64;

  // ---- setup: flag, small converts, weight transposes, wsum ----
  k_flag<<<1,64,0,stream>>>(d_in[11], flag);
  k_cvt<<<(12672+255)/256,256,0,stream>>>(d_in[8],  rel_b, 12672, flag);
  k_cvt<<<(3072+255)/256,256,0,stream>>>(d_in[10], bo_b,  3072, flag);
  k_cvt<<<(3072+255)/256,256,0,stream>>>(d_in[11], g1_b,  3072, flag);
  k_cvt<<<(3072+255)/256,256,0,stream>>>(d_in[12], be1_b, 3072, flag);
  k_cvt<<<(3072+255)/256,256,0,stream>>>(d_in[13], g2_b,  3072, flag);
  k_cvt<<<(3072+255)/256,256,0,stream>>>(d_in[14], be2_b, 3072, flag);
  k_cvt<<<(12288+255)/256,256,0,stream>>>(d_in[16], b1_b, 12288, flag);
  k_cvt<<<(3072+255)/256,256,0,stream>>>(d_in[18], b2_b,  3072, flag);
  k_cvt<<<(2048+255)/256,256,0,stream>>>(d_in[20], bout_b, 2048, flag);
  k_packb<<<(LL*192+255)/256,256,0,stream>>>(d_in[3], d_in[5], d_in[7], bqkv, flag);
  k_tr<<<dim3(2,16,LL),256,0,stream>>>(d_in[2], WqkvT,            512, 64, 512*64, 3*64*512, 512, flag);
  k_tr<<<dim3(2,16,LL),256,0,stream>>>(d_in[4], WqkvT + 64*512,   512, 64, 512*64, 3*64*512, 512, flag);
  k_tr<<<dim3(2,16,LL),256,0,stream>>>(d_in[6], WqkvT + 2*64*512, 512, 64, 512*64, 3*64*512, 512, flag);
  k_tr<<<dim3(64,16,LL),256,0,stream>>>(d_in[15], W1T, 512, 2048, 512*2048, 2048*512, 512, flag);
  k_tr<<<dim3(16,64,LL),256,0,stream>>>(d_in[17], W2T, 2048, 512, 2048*512, 512*2048, 2048, flag);
  k_tr<<<dim3(64,16,1),256,0,stream>>>(d_in[19], WoutT, 512, 2048, 0, 0, 512, flag);
  k_wsumT<<<(LL*32768+255)/256,256,0,stream>>>(d_in[9], wsT_all, flag);

  k_embed<<<BT,256,0,stream>>>(idx, d_in[1], h, flag);

  for(int l=0; l<LL; ++l){
    k_ln<<<BT,256,0,stream>>>(h, g1_b+l*DD, be1_b+l*DD, y);
    // QKV: batched z=3
    mm<128,64,64,4,1,0,false,false><<<dim3(64,1,3),256,0,stream>>>(
        y, WqkvT + (size_t)l*3*64*512, QKV, bqkv + l*192,
        BT, 64, 512, 0, 64*512, (long long)BT*64, 64, 1, nullptr);
    // scores = Q @ K^T (bf16, d_out scratch), z=16
    mm<128,128,64,2,2,0,false,false><<<dim3(16,1,16),256,0,stream>>>(
        Qb, Kb, scores, nullptr,
        512, 512, 64, (long long)512*64, (long long)512*64, (long long)512*512, 0, 4, nullptr);
    // softmax + merged Qrel + bucket sums -> att_aug (overwrites y)
    k_softmax<<<BT,256,0,stream>>>(scores, Qb, rel_b + l*33*64, att);
    // V [16][512][64] -> VbT_aug cols 0..511 ; rel^T -> cols 512..575
    k_tr<<<dim3(2,16,BB),256,0,stream>>>(QKV + (size_t)2*BT*64, VbT, 512, 64, 512*64, 64*576, 576, nullptr);
    k_relfill<<<(BB*64*64+255)/256,256,0,stream>>>(rel_b + l*33*64, VbT);
    // vals = att_aug @ VbT_aug^T  (fused PV + rel-bias), z=16, K=576
    mm<64,64,64,2,2,0,false,false><<<dim3(8,1,16),256,0,stream>>>(
        att, VbT, vals, nullptr,
        512, 64, 576, (long long)512*576, (long long)64*576, (long long)512*64, 0, 1, nullptr);
    // h += vals @ WsumT + bo
    mm<128,128,64,2,2,1,false,true><<<dim3(256,1,1),256,0,stream>>>(
        vals, wsT_all + (size_t)l*32768, h, bo_b + l*DD, BT, 512, 64, 0,0,0,0, 4, nullptr);
    k_ln<<<BT,256,0,stream>>>(h, g2_b+l*DD, be2_b+l*DD, y);
    // mid = relu(y @ W1 + b1)   (bf16, d_out scratch)
    mm<128,128,64,2,2,0,true,false><<<dim3(1024,1,1),256,0,stream>>>(
        y, W1T + (size_t)l*2048*512, mid, b1_b + l*FF, BT, 2048, 512, 0,0,0,0, 16, nullptr);
    // h += mid @ W2 + b2
    mm<128,128,64,2,2,1,false,true><<<dim3(256,1,1),256,0,stream>>>(
        mid, W2T + (size_t)l*512*2048, h, b2_b + l*DD, BT, 512, 2048, 0,0,0,0, 4, nullptr);
  }
  k_f2b<<<(BT*DD+255)/256,256,0,stream>>>(h, hb, BT*DD);
  // out = hb @ Wout + bout (dual store per flag; fully rewrites d_out)
  mm<128,128,64,2,2,2,false,false><<<dim3(1024,1,1),256,0,stream>>>(
      hb, WoutT, d_out, bout_b, BT, 2048, 512, 0,0,0,0, 16, flag);
}

// Round 7
// 979.884 us; speedup vs baseline: 1.1268x; 1.1268x over previous
//
#include <hip/hip_runtime.h>
#include <hip/hip_bf16.h>
#include <math.h>

#define BB 16
#define TT 512
#define VV 2048
#define DD 512
#define HDD 64
#define LL 6
#define FF 2048
#define BT 8192   // B*T

typedef __hip_bfloat16 bf16;
typedef __attribute__((ext_vector_type(8))) short bf8s;   // 8 bf16 (4 VGPRs)
typedef __attribute__((ext_vector_type(4))) float f4;     // C/D frag

__device__ __forceinline__ float cvt(float x){ return x; }
__device__ __forceinline__ float cvt(bf16 x){ return __bfloat162float(x); }

// async global->LDS, 16B per lane. LDS dest must be wave-uniform base (+lane*16 by HW).
__device__ __forceinline__ void gl16(const bf16* g, bf16* l){
  __builtin_amdgcn_global_load_lds(
      (const __attribute__((address_space(1))) void*)g,
      (__attribute__((address_space(3))) void*)l,
      16, 0, 0);
}

// ---------------- dtype flag: g1 all-ones. f32 1.0f -> u16 {0,0x3F80}; bf16 1.0 -> 0x3F80 ----------------
__global__ void k_flag(const void* g1, int* flagp){
  if(threadIdx.x==0 && blockIdx.x==0){
    const unsigned short* u = (const unsigned short*)g1;
    *flagp = (u[0] == 0) ? 1 : 0;   // 1 = inputs f32, 0 = bf16
  }
}

// ---------------- convert flag-typed input to bf16 copy ----------------
__global__ __launch_bounds__(256) void k_cvt(const void* __restrict__ src,
                                             bf16* __restrict__ dst, int n,
                                             const int* __restrict__ flagp){
  int i = blockIdx.x*256 + threadIdx.x;
  if(i >= n) return;
  if(*flagp) dst[i] = (bf16)(((const float*)src)[i]);
  else       dst[i] = ((const bf16*)src)[i];
}

// ---------------- pack QKV biases: [L][64]x3 -> [L][3][64] bf16 ----------------
__global__ void k_packb(const void* bq, const void* bk, const void* bv,
                        bf16* dst, const int* flagp){
  int i = blockIdx.x*256 + threadIdx.x;
  if(i >= LL*192) return;
  int l = i/192, r = i%192, j = r>>6, hh = r&63;
  const void* s = (j==0)?bq:((j==1)?bk:bv);
  float v = (*flagp) ? ((const float*)s)[l*64+hh] : cvt(((const bf16*)s)[l*64+hh]);
  dst[i] = (bf16)v;
}

// ---------------- tiled transpose: src [z][R][C] -> dst [z][C][R(ldD)] bf16 ----------------
__global__ __launch_bounds__(256) void k_tr(const void* __restrict__ src, bf16* __restrict__ dst,
                                            int R, int C, long long sS, long long sD, int ldD,
                                            const int* __restrict__ flagp){
  __shared__ bf16 t[32][33];
  int z = blockIdx.z;
  int c0 = blockIdx.x*32, r0 = blockIdx.y*32;
  int tx = threadIdx.x & 31, ty = threadIdx.x >> 5;   // 32 x 8
  bool isf = flagp && (*flagp);
  const float* sf = (const float*)src;
  const bf16*  sb = (const bf16*)src;
  for(int i=ty; i<32; i+=8){
    size_t off = (size_t)z*sS + (size_t)(r0+i)*C + (c0+tx);
    float v = isf ? sf[off] : cvt(sb[off]);
    t[i][tx] = (bf16)v;
  }
  __syncthreads();
  for(int i=ty; i<32; i+=8){
    dst[(size_t)z*sD + (size_t)(c0+i)*ldD + (r0+tx)] = t[tx][i];
  }
}

// ---------------- wsT_all[l][d][h] = sum_n Wo[l][n*64+h][d], all layers ----------------
__global__ __launch_bounds__(256) void k_wsumT(const void* __restrict__ Wo,
                                               bf16* __restrict__ wsT,
                                               const int* __restrict__ flagp){
  int i = blockIdx.x*256 + threadIdx.x;   // 6*64*512
  if(i >= LL*64*512) return;
  int l = i >> 15, j = i & 32767, hh = j>>9, d = j&511;
  size_t loff = (size_t)l*512*512;
  bool isf = *flagp;
  float a = 0.f;
  #pragma unroll
  for(int n=0;n<8;++n){
    size_t idx = loff + (size_t)(n*64+hh)*512 + d;
    a += isf ? ((const float*)Wo)[idx] : cvt(((const bf16*)Wo)[idx]);
  }
  wsT[(size_t)l*32768 + d*64 + hh] = (bf16)a;
}

// ---------------- fill VbT_aug cols 512..575 with rel^T (m<17) else 0 ----------------
__global__ __launch_bounds__(256) void k_relfill(const bf16* __restrict__ rel,
                                                 bf16* __restrict__ vt){
  int i = blockIdx.x*256 + threadIdx.x;   // 16*64*64
  if(i >= BB*64*64) return;
  int z = i >> 12, rest = i & 4095, hh = rest >> 6, j = rest & 63;
  vt[(size_t)z*64*576 + (size_t)hh*576 + 512 + j] = (j<17) ? rel[j*64+hh] : (bf16)0.f;
}

// ---------------- embed + positional encoding: h = 2*emb[idx] + pe ----------------
__global__ __launch_bounds__(256) void k_embed(const int* __restrict__ idx,
                                               const void* __restrict__ emb,
                                               float* __restrict__ h,
                                               const int* __restrict__ flagp){
  int r = blockIdx.x;
  int t = r & (TT-1);
  int tok = idx[r];
  bool isf = *flagp;
  for(int d = threadIdx.x; d < DD; d += 256){
    int p = d >> 1;
    float ang = (float)t * powf(10000.f, -(float)p * (1.f/128.f));
    float pe = (d & 1) ? cosf(ang) : sinf(ang);
    size_t off = (size_t)tok*DD + d;
    float ev = isf ? ((const float*)emb)[off] : cvt(((const bf16*)emb)[off]);
    h[(size_t)r*DD + d] = 2.f*ev + pe;
  }
}

// ---------------- LayerNorm (biased var): f32 in, bf16 out ----------------
__global__ __launch_bounds__(256) void k_ln(const float* __restrict__ x,
                                            const bf16* __restrict__ g,
                                            const bf16* __restrict__ b,
                                            bf16* __restrict__ y){
  int r = blockIdx.x;
  int tid = threadIdx.x;
  const float* xr = x + (size_t)r*DD;
  float v0 = xr[tid], v1 = xr[tid+256];
  float s = v0+v1, s2 = v0*v0 + v1*v1;
  for(int o=32;o;o>>=1){ s += __shfl_down(s,o); s2 += __shfl_down(s2,o); }
  __shared__ float red[8];
  int wv = tid>>6, ln = tid&63;
  if(ln==0){ red[wv]=s; red[4+wv]=s2; }
  __syncthreads();
  float a  = red[0]+red[1]+red[2]+red[3];
  float a2 = red[4]+red[5]+red[6]+red[7];
  float m  = a*(1.f/DD);
  float var = a2*(1.f/DD) - m*m;
  float inv = rsqrtf(var + 1e-5f);
  y[(size_t)r*DD+tid]     = (bf16)((v0-m)*inv*cvt(g[tid])     + cvt(b[tid]));
  y[(size_t)r*DD+tid+256] = (bf16)((v1-m)*inv*cvt(g[tid+256]) + cvt(b[tid+256]));
}

// ---------------- f32 -> bf16 ----------------
__global__ __launch_bounds__(256) void k_f2b(const float* __restrict__ x, bf16* __restrict__ o, int n){
  int i = blockIdx.x*256 + threadIdx.x;
  if(i < n) o[i] = (bf16)x[i];
}

// =====================  MFMA GEMM v2  =====================
// C[M,N] (=|+=) A[M,K] @ Bt[N,K]^T, bf16, f32 accum.
// global_load_lds (16B) staging, double-buffered LDS, ONE barrier per K-step.
// Granule swizzle: LDS linear dest; global source granule ^= (row&7); ds_read applies same XOR.
// 1-D grid per z with bijective XCD-chunked swizzle (x fastest). BK=64 fixed.
// CMODE: 0 = bf16 store, 1 = f32 store (+RESID reads f32), 2 = dual via flag.
template<int BM,int BN,int WM,int WN,int CMODE,bool RELU,bool RESID>
__global__ __launch_bounds__(256) void mm(const bf16* __restrict__ A,
                                          const bf16* __restrict__ Bt,
                                          void* __restrict__ Cv,
                                          const bf16* __restrict__ bias,
                                          int M, int N, int K,
                                          long long sA, long long sB, long long sC, int sBias,
                                          int gx,
                                          const int* __restrict__ flagp){
  constexpr int BK  = 64;
  constexpr int FM  = BM/(WM*16);
  constexpr int FN  = BN/(WN*16);
  constexpr int S   = (BM+BN)*BK;        // elems per LDS buffer
  constexpr int CAW = (BM*BK/512)/4;     // 1024B chunks per wave (A)
  constexpr int CBW = (BN*BK/512)/4;
  __shared__ bf16 lds[2*S];
  // XCD-chunked bijective swizzle (m204)
  int nwg = gridDim.x, bid = blockIdx.x;
  int q = nwg>>3, rr = nwg&7, xcd = bid&7, ii = bid>>3;
  int wg = (xcd<rr ? xcd*(q+1) : rr*(q+1)+(xcd-rr)*q) + ii;
  int bx = wg % gx, by = wg / gx;
  int z = blockIdx.z;
  A  += (size_t)z*sA;
  Bt += (size_t)z*sB;
  if(bias) bias += (size_t)z*sBias;
  int tid = threadIdx.x, lane = tid&63, w = tid>>6;
  int m0 = by*BM, n0 = bx*BN;
  int wrow = (w/WN)*(FM*16), wcol = (w%WN)*(FN*16);
  int l15 = lane&15, l4 = lane>>4;
  int lrow = lane>>3, lgr = lane&7;      // stage: row-in-chunk, granule
  int nk = K/BK;
  auto stage = [&](int kt, int buf){
    bf16* Ab = lds + buf*S;
    bf16* Bb = Ab + BM*BK;
    const bf16* gA = A + (size_t)m0*K + kt*BK;
    const bf16* gB = Bt + (size_t)n0*K + kt*BK;
    #pragma unroll
    for(int i=0;i<CAW;++i){
      int chunk = w*CAW + i;             // wave-uniform
      int row = chunk*8 + lrow;
      gl16(gA + (size_t)row*K + ((lgr ^ (row&7))*8), Ab + chunk*512);
    }
    #pragma unroll
    for(int i=0;i<CBW;++i){
      int chunk = w*CBW + i;
      int row = chunk*8 + lrow;
      gl16(gB + (size_t)row*K + ((lgr ^ (row&7))*8), Bb + chunk*512);
    }
  };
  f4 acc[FM][FN] = {};
  stage(0, 0);
  __syncthreads();
  for(int kt=0; kt<nk; ++kt){
    int cur = kt & 1;
    if(kt+1 < nk) stage(kt+1, cur^1);    // async loads overlap MFMA below
    const bf16* Ab = lds + cur*S;
    const bf16* Bb = Ab + BM*BK;
    #pragma unroll
    for(int g=0; g<2; ++g){
      bf8s af[FM], bfv[FN];
      #pragma unroll
      for(int i=0;i<FM;++i){
        int r = wrow + i*16 + l15;
        af[i] = *(const bf8s*)(Ab + r*BK + (((g*4+l4) ^ (r&7))*8));
      }
      #pragma unroll
      for(int j=0;j<FN;++j){
        int r = wcol + j*16 + l15;
        bfv[j] = *(const bf8s*)(Bb + r*BK + (((g*4+l4) ^ (r&7))*8));
      }
      #pragma unroll
      for(int i=0;i<FM;++i)
        #pragma unroll
        for(int j=0;j<FN;++j)
          acc[i][j] = __builtin_amdgcn_mfma_f32_16x16x32_bf16(af[i], bfv[j], acc[i][j], 0,0,0);
    }
    __syncthreads();                     // drains stage vmcnt + guards both buffers
  }
  bool f32o = (CMODE==2) ? (*flagp != 0) : (CMODE==1);
  #pragma unroll
  for(int i=0;i<FM;++i){
    #pragma unroll
    for(int j=0;j<FN;++j){
      int col = n0 + wcol + j*16 + l15;
      float bv = bias ? cvt(bias[col]) : 0.f;
      #pragma unroll
      for(int q2=0;q2<4;++q2){
        int row = m0 + wrow + i*16 + l4*4 + q2;
        size_t off = (size_t)z*sC + (size_t)row*N + col;
        float v = acc[i][j][q2] + bv;
        if(RESID) v += ((const float*)Cv)[off];
        if(RELU)  v = fmaxf(v, 0.f);
        if(CMODE==0)      ((bf16*)Cv)[off] = (bf16)v;
        else if(CMODE==1) ((float*)Cv)[off] = v;
        else { if(f32o) ((float*)Cv)[off] = v; else ((bf16*)Cv)[off] = (bf16)v; }
      }
    }
  }
}

// ---------------- softmax: bf16 scores + Qrel (merged) + causal + aug-row write ----------------
__global__ __launch_bounds__(256) void k_softmax(const bf16* __restrict__ scores,
                                                 const bf16* __restrict__ Q,
                                                 const bf16* __restrict__ rel,   // layer base [33][64]
                                                 bf16* __restrict__ att){
  int r = blockIdx.x;            // b*512 + t
  int t = r & 511;
  int tid = threadIdx.x;
  __shared__ float qs[64], qrs[17], red[8], am_s[17];
  if(tid >= 128 && tid < 192) qs[tid-128] = cvt(Q[(size_t)r*64 + (tid-128)]);
  if(tid >= 32 && tid < 49) am_s[tid-32] = 0.f;
  __syncthreads();
  if(tid < 17){
    float a = 0.f;
    #pragma unroll
    for(int hh=0;hh<64;++hh) a += qs[hh]*cvt(rel[tid*64+hh]);
    qrs[tid] = a;
  }
  __syncthreads();
  const bf16* srow = scores + (size_t)r*512;
  float sc[2];
  #pragma unroll
  for(int ii=0; ii<2; ++ii){
    int s = tid + ii*256;
    float v = -INFINITY;
    if(s <= t){
      int m = s - t + 16; m = m < 0 ? 0 : m;
      v = (cvt(srow[s]) + qrs[m])*0.125f;
    }
    sc[ii] = v;
  }
  int wv = tid>>6, ln = tid&63;
  float mx = fmaxf(sc[0], sc[1]);
  for(int o=32;o;o>>=1) mx = fmaxf(mx, __shfl_down(mx,o));
  if(ln==0) red[wv]=mx;
  __syncthreads();
  float M = fmaxf(fmaxf(red[0],red[1]),fmaxf(red[2],red[3]));
  float e0 = expf(sc[0]-M), e1 = expf(sc[1]-M);
  float sum = e0+e1;
  for(int o=32;o;o>>=1) sum += __shfl_down(sum,o);
  __syncthreads();
  if(ln==0) red[wv]=sum;
  __syncthreads();
  float rs = 1.f/(red[0]+red[1]+red[2]+red[3]);
  bf16* arow = att + (size_t)r*576;
  float part0 = 0.f;
  #pragma unroll
  for(int ii=0;ii<2;++ii){
    int s = tid + ii*256;
    float p = (ii==0 ? e0 : e1)*rs;
    arow[s] = (bf16)p;
    if(s <= t){
      int m = s - t + 16;
      if(m <= 0) part0 += p;
      else       am_s[m] = p;
    }
  }
  for(int o=32;o;o>>=1) part0 += __shfl_down(part0,o);
  __syncthreads();
  if(ln==0) red[wv]=part0;
  __syncthreads();
  if(tid==0) am_s[0] = red[0]+red[1]+red[2]+red[3];
  __syncthreads();
  if(tid<64) arow[512+tid] = (tid<17) ? (bf16)am_s[tid] : (bf16)0.f;
}

extern "C" void kernel_launch(void* const* d_in, const int* in_sizes, int n_in,
                              void* d_out, int out_size, void* d_ws, size_t ws_size,
                              hipStream_t stream){
  const int* idx = (const int*)d_in[0];

  char* p = (char*)d_ws;
  auto alloc = [&](size_t bytes)->char*{ char* r = p; p += (bytes + 255) & ~(size_t)255; return r; };

  int*  flag  = (int*)alloc(4);
  bf16* rel_b = (bf16*)alloc(12672*2);
  bf16* bo_b  = (bf16*)alloc(3072*2);
  bf16* g1_b  = (bf16*)alloc(3072*2);
  bf16* be1_b = (bf16*)alloc(3072*2);
  bf16* g2_b  = (bf16*)alloc(3072*2);
  bf16* be2_b = (bf16*)alloc(3072*2);
  bf16* b1_b  = (bf16*)alloc(12288*2);
  bf16* b2_b  = (bf16*)alloc(3072*2);
  bf16* bout_b= (bf16*)alloc(2048*2);
  bf16* bqkv  = (bf16*)alloc(LL*192*2);
  bf16* WqkvT = (bf16*)alloc((size_t)LL*3*64*512*2);    // [L][3][64][512]
  bf16* W1T   = (bf16*)alloc((size_t)LL*2048*512*2);    // [L][2048][512]
  bf16* W2T   = (bf16*)alloc((size_t)LL*512*2048*2);    // [L][512][2048]
  bf16* WoutT = (bf16*)alloc((size_t)2048*512*2);       // [2048][512]
  bf16* wsT_all=(bf16*)alloc((size_t)LL*512*64*2);      // [L][512][64]
  float* h    = (float*)alloc((size_t)BT*DD*4);         // 16 MB
  bf16*  y    = (bf16*) alloc((size_t)BB*512*576*2);    // 9.4 MB (y | att_aug | hb union)
  bf16*  att  = y;                                      // att_aug [16][512][576]
  bf16*  hb   = y;
  bf16*  QKV  = (bf16*) alloc((size_t)3*BT*64*2);       // Q|K|V contiguous
  bf16*  vals = (bf16*) alloc((size_t)BT*64*2);
  bf16*  VbT  = (bf16*) alloc((size_t)BB*64*576*2);     // [16][64][576] (V^T | rel^T aug)
  // d_out scratch (disjoint lifetimes): scores bf16 8.4 MB -> mid bf16 33.5 MB -> final output
  bf16* scores = (bf16*)d_out;
  bf16* mid    = (bf16*)d_out;
  bf16* Qb = QKV, *Kb = QKV + (size_t)BT*64;

  // ---- setup ----
  k_flag<<<1,64,0,stream>>>(d_in[11], flag);
  k_cvt<<<(12672+255)/256,256,0,stream>>>(d_in[8],  rel_b, 12672, flag);
  k_cvt<<<(3072+255)/256,256,0,stream>>>(d_in[10], bo_b,  3072, flag);
  k_cvt<<<(3072+255)/256,256,0,stream>>>(d_in[11], g1_b,  3072, flag);
  k_cvt<<<(3072+255)/256,256,0,stream>>>(d_in[12], be1_b, 3072, flag);
  k_cvt<<<(3072+255)/256,256,0,stream>>>(d_in[13], g2_b,  3072, flag);
  k_cvt<<<(3072+255)/256,256,0,stream>>>(d_in[14], be2_b, 3072, flag);
  k_cvt<<<(12288+255)/256,256,0,stream>>>(d_in[16], b1_b, 12288, flag);
  k_cvt<<<(3072+255)/256,256,0,stream>>>(d_in[18], b2_b,  3072, flag);
  k_cvt<<<(2048+255)/256,256,0,stream>>>(d_in[20], bout_b, 2048, flag);
  k_packb<<<(LL*192+255)/256,256,0,stream>>>(d_in[3], d_in[5], d_in[7], bqkv, flag);
  k_tr<<<dim3(2,16,LL),256,0,stream>>>(d_in[2], WqkvT,            512, 64, 512*64, 3*64*512, 512, flag);
  k_tr<<<dim3(2,16,LL),256,0,stream>>>(d_in[4], WqkvT + 64*512,   512, 64, 512*64, 3*64*512, 512, flag);
  k_tr<<<dim3(2,16,LL),256,0,stream>>>(d_in[6], WqkvT + 2*64*512, 512, 64, 512*64, 3*64*512, 512, flag);
  k_tr<<<dim3(64,16,LL),256,0,stream>>>(d_in[15], W1T, 512, 2048, 512*2048, 2048*512, 512, flag);
  k_tr<<<dim3(16,64,LL),256,0,stream>>>(d_in[17], W2T, 2048, 512, 2048*512, 512*2048, 2048, flag);
  k_tr<<<dim3(64,16,1),256,0,stream>>>(d_in[19], WoutT, 512, 2048, 0, 0, 512, flag);
  k_wsumT<<<(LL*32768+255)/256,256,0,stream>>>(d_in[9], wsT_all, flag);

  k_embed<<<BT,256,0,stream>>>(idx, d_in[1], h, flag);

  for(int l=0; l<LL; ++l){
    k_ln<<<BT,256,0,stream>>>(h, g1_b+l*DD, be1_b+l*DD, y);
    // QKV: batched z=3, N=64
    mm<128,64,4,1,0,false,false><<<dim3(64,1,3),256,0,stream>>>(
        y, WqkvT + (size_t)l*3*64*512, QKV, bqkv + l*192,
        BT, 64, 512, 0, 64*512, (long long)BT*64, 64, 1, nullptr);
    // scores = Q @ K^T (bf16, d_out scratch), z=16
    mm<128,64,4,1,0,false,false><<<dim3(32,1,16),256,0,stream>>>(
        Qb, Kb, scores, nullptr,
        512, 512, 64, (long long)512*64, (long long)512*64, (long long)512*512, 0, 8, nullptr);
    // softmax + merged Qrel + bucket sums -> att_aug (overwrites y)
    k_softmax<<<BT,256,0,stream>>>(scores, Qb, rel_b + l*33*64, att);
    // V [16][512][64] -> VbT_aug cols 0..511 ; rel^T -> cols 512..575
    k_tr<<<dim3(2,16,BB),256,0,stream>>>(QKV + (size_t)2*BT*64, VbT, 512, 64, 512*64, 64*576, 576, nullptr);
    k_relfill<<<(BB*64*64+255)/256,256,0,stream>>>(rel_b + l*33*64, VbT);
    // vals = att_aug @ VbT_aug^T  (fused PV + rel-bias), z=16, K=576
    mm<64,64,2,2,0,false,false><<<dim3(8,1,16),256,0,stream>>>(
        att, VbT, vals, nullptr,
        512, 64, 576, (long long)512*576, (long long)64*576, (long long)512*64, 0, 1, nullptr);
    // h += vals @ WsumT + bo
    mm<128,64,4,1,1,false,true><<<dim3(512,1,1),256,0,stream>>>(
        vals, wsT_all + (size_t)l*32768, h, bo_b + l*DD, BT, 512, 64, 0,0,0,0, 8, nullptr);
    k_ln<<<BT,256,0,stream>>>(h, g2_b+l*DD, be2_b+l*DD, y);
    // mid = relu(y @ W1 + b1)   (bf16, d_out scratch)
    mm<128,64,4,1,0,true,false><<<dim3(2048,1,1),256,0,stream>>>(
        y, W1T + (size_t)l*2048*512, mid, b1_b + l*FF, BT, 2048, 512, 0,0,0,0, 32, nullptr);
    // h += mid @ W2 + b2
    mm<128,64,4,1,1,false,true><<<dim3(512,1,1),256,0,stream>>>(
        mid, W2T + (size_t)l*512*2048, h, b2_b + l*DD, BT, 512, 2048, 0,0,0,0, 8, nullptr);
  }
  k_f2b<<<(BT*DD+255)/256,256,0,stream>>>(h, hb, BT*DD);
  // out = hb @ Wout + bout (dual store per flag; fully rewrites d_out)
  mm<128,64,4,1,2,false,false><<<dim3(2048,1,1),256,0,stream>>>(
      hb, WoutT, d_out, bout_b, BT, 2048, 512, 0,0,0,0, 32, flag);
}